// Round 12
// baseline (129.860 us; speedup 1.0000x reference)
//
#include <hip/hip_runtime.h>
#include <hip/hip_bf16.h>
#include <math.h>

#define NTILES 64
#define TPC 8
#define NCLUST 8
#define GRID_SZ 16
#define DIM 512
#define DHID 128
#define NTOK 2048
#define LN_EPS 1e-5f
#define TB 16             // tokens per chunk == MFMA M-tile
#define NCHUNK_MAX 192    // sum ceil(cnt/16) <= 128 + 60 < 192 = 8*24
#define NBLK 1024

// flag slots, 64B apart (own cachelines)
#define FA1 0
#define FA2 16
#define FB  32
#define FC  48

typedef __attribute__((ext_vector_type(8))) short bf16x8;
typedef __attribute__((ext_vector_type(4))) float f32x4;

static __device__ __forceinline__ float fsign(float v) {
    return (v > 0.f) ? 1.f : ((v < 0.f) ? -1.f : 0.f);
}

static __device__ __forceinline__ unsigned short bf16bits(float f) {
    union { __hip_bfloat16 h; unsigned short s; } u;
    u.h = __float2bfloat16(f);
    return u.s;
}

static __device__ __forceinline__ bf16x8 cvt8(const float* p) {
    float4 a = *(const float4*)p;
    float4 b = *(const float4*)(p + 4);
    float e[8] = {a.x, a.y, a.z, a.w, b.x, b.y, b.z, b.w};
    bf16x8 v;
    #pragma unroll
    for (int i = 0; i < 8; ++i) v[i] = (short)bf16bits(e[i]);
    return v;
}

// tid==0 only: spin until flag >= target (relaxed atomic read + sleep backoff)
static __device__ __forceinline__ void wait_flag(int* f, int target) {
    while (atomicAdd(f, 0) < target) __builtin_amdgcn_s_sleep(8);
}

__global__ __launch_bounds__(256, 4) void k_all(const float* __restrict__ x,
                                                const float* __restrict__ gamma,
                                                const float* __restrict__ beta,
                                                const float* __restrict__ Wd,
                                                const float* __restrict__ sb,
                                                const float* __restrict__ ss,
                                                const float* __restrict__ Wu,
                                                const float* __restrict__ scale,
                                                float* __restrict__ out,
                                                int* __restrict__ flags,
                                                float* __restrict__ psum,
                                                float* __restrict__ tile_sigs,
                                                float* __restrict__ cluster_sigs,
                                                int* __restrict__ counts,
                                                int* __restrict__ list,
                                                unsigned short* __restrict__ xn_b,
                                                unsigned short* __restrict__ wd_b,
                                                unsigned short* __restrict__ wu_b) {
    int b = blockIdx.x;
    int tid = threadIdx.x;
    int lane = tid & 63;
    int wv = tid >> 6;

    // ===== phase 1 =====
    if (b < 512) {
        // Wd column psums (16 dh rows) + bf16 Wd copy
        int t = b >> 3, part = b & 7;
        const float* basep = Wd + ((size_t)t * DHID + part * 16) * DIM;
        unsigned short* bb = wd_b + ((size_t)t * DHID + part * 16) * DIM;
        #pragma unroll
        for (int k2 = 0; k2 < 2; ++k2) {
            int d = tid + k2 * 256;
            float s = 0.f;
            #pragma unroll
            for (int j = 0; j < 16; ++j) {
                float v = basep[(size_t)j * DIM + d];
                s += v;
                bb[(size_t)j * DIM + d] = bf16bits(v);
            }
            psum[((size_t)t * 8 + part) * DIM + d] = s;
        }
    } else {
        // LayerNorm (4 tokens, 1/wave) then Wu bf16 copy (8192 floats)
        int n = (b - 512) * 4 + wv;
        const float* xr = x + (size_t)n * DIM;
        float v[8];
        float sum = 0.f;
        #pragma unroll
        for (int j = 0; j < 8; ++j) { float t = xr[lane + 64 * j]; v[j] = t; sum += t; }
        #pragma unroll
        for (int off = 32; off; off >>= 1) sum += __shfl_xor(sum, off);
        float mu = sum * (1.f / DIM);
        float sq = 0.f;
        #pragma unroll
        for (int j = 0; j < 8; ++j) { float t = v[j] - mu; sq += t * t; }
        #pragma unroll
        for (int off = 32; off; off >>= 1) sq += __shfl_xor(sq, off);
        float rs = rsqrtf(sq * (1.f / DIM) + LN_EPS);
        #pragma unroll
        for (int j = 0; j < 8; ++j) {
            int d = lane + 64 * j;
            float xv = (v[j] - mu) * rs * gamma[d] + beta[d];
            xn_b[(size_t)n * DIM + d] = bf16bits(xv);
        }
        size_t basei = (size_t)(b - 512) * 8192;
        #pragma unroll
        for (int k = 0; k < 4; ++k) {
            size_t off = basei + (size_t)tid * 8 + (size_t)k * 2048;
            *(bf16x8*)(wu_b + off) = cvt8(Wu + off);
        }
    }
    __syncthreads();
    if (tid == 0) {
        __threadfence();                       // release: psum/wd_b/xn_b/wu_b
        atomicAdd(&flags[b < 512 ? FA1 : FA2], 1);
    }
    if (b >= 512) return;

    // ===== phase 2: csig (blocks 0..7, cluster b) =====
    if (b < NCLUST) {
        if (tid == 0) { wait_flag(&flags[FA1], 512); __threadfence(); }  // acquire psum
        __syncthreads();
        if (tid < TPC) counts[b * TPC + tid] = 0;   // zero my cluster's tile counts
        #pragma unroll
        for (int k2 = 0; k2 < 2; ++k2) {
            int d = tid + k2 * 256;
            float csum = 0.f;
            #pragma unroll
            for (int k = 0; k < TPC; ++k) {
                int t = b * TPC + k;
                float s = 0.f;
                #pragma unroll
                for (int p = 0; p < 8; ++p) s += psum[((size_t)t * 8 + p) * DIM + d];
                float sg = fsign(s);
                tile_sigs[(size_t)t * DIM + d] = sg;
                csum += sg;
            }
            cluster_sigs[(size_t)b * DIM + d] = fsign(csum);
        }
        __syncthreads();
        if (tid == 0) { __threadfence(); atomicAdd(&flags[FB], 1); }
    }

    // ===== phase 3: route (blocks 0..511, 4 tokens each) =====
    if (tid == 0) {
        wait_flag(&flags[FB], NCLUST);
        wait_flag(&flags[FA2], 512);
        __threadfence();                       // acquire sigs + counts-zero + xn_b
    }
    __syncthreads();
    {
        int n = b * 4 + wv;
        float sg[8];
        #pragma unroll
        for (int j = 0; j < 8; ++j) {
            unsigned short u = xn_b[(size_t)n * DIM + lane + 64 * j];
            sg[j] = ((u & 0x7fff) == 0) ? 0.f : ((u & 0x8000) ? -1.f : 1.f);
        }
        int best_c = 0; float best = -1e30f;
        for (int c = 0; c < NCLUST; ++c) {
            float s = 0.f;
            #pragma unroll
            for (int j = 0; j < 8; ++j) s += sg[j] * cluster_sigs[(size_t)c * DIM + lane + 64 * j];
            #pragma unroll
            for (int off = 32; off; off >>= 1) s += __shfl_xor(s, off);
            if (s > best) { best = s; best_c = c; }
        }
        int bt = best_c * TPC; float bts = -1e30f;
        for (int k = 0; k < TPC; ++k) {
            int t = best_c * TPC + k;
            float s = 0.f;
            #pragma unroll
            for (int j = 0; j < 8; ++j) s += sg[j] * tile_sigs[(size_t)t * DIM + lane + 64 * j];
            #pragma unroll
            for (int off = 32; off; off >>= 1) s += __shfl_xor(s, off);
            if (s > bts) { bts = s; bt = t; }
        }
        if (lane == 0) {
            int slot = atomicAdd(&counts[bt], 1);
            list[(size_t)bt * NTOK + slot] = n;
        }
    }
    __syncthreads();
    if (tid == 0) { __threadfence(); atomicAdd(&flags[FC], 1); }
    if (b >= NCHUNK_MAX) return;

    // ===== phase 4: ffn (blocks 0..191, one 16-token chunk) =====
    if (tid == 0) { wait_flag(&flags[FC], 512); __threadfence(); }   // acquire counts/list
    __syncthreads();

    int cb = (b & 7) * (NCHUNK_MAX / 8) + (b >> 3);   // same-tile chunks -> same XCD
    // in-wave self-routing with atomic count reads
    int t, base, m;
    {
        int cnt_l = atomicAdd(&counts[lane], 0);
        int nck = (cnt_l + TB - 1) / TB;
        int pre = nck;
        #pragma unroll
        for (int off = 1; off < 64; off <<= 1) {
            int u = __shfl_up(pre, off);
            if (lane >= off) pre += u;
        }
        int total = __shfl(pre, 63);
        pre -= nck;
        if (cb >= total) return;
        unsigned long long msk = __ballot(cb >= pre && cb < pre + nck);
        t = (int)__builtin_ctzll(msk);
        base = (cb - __shfl(pre, t)) * TB;
        m = min(TB, __shfl(cnt_l, t) - base);
    }

    __shared__ __align__(16) unsigned short hsl[TB * DHID];   // bf16, XOR-swizzled

    int mrow = lane & 15;
    int ko = (lane >> 4) * 8;
    int tokm = list[(size_t)t * NTOK + base + min(mrow, m - 1)];
    const unsigned short* xr = xn_b + (size_t)tokm * DIM;

    // ---- down: wave wv does dh-tiles {wv, wv+4} (16 MFMA each, K=512) ----
    #pragma unroll
    for (int j = 0; j < 2; ++j) {
        int dtile = wv + j * 4;
        const unsigned short* wr = wd_b + ((size_t)t * DHID + dtile * 16 + mrow) * DIM;
        f32x4 acc = {0.f, 0.f, 0.f, 0.f};
        #pragma unroll
        for (int kk = 0; kk < 16; ++kk) {
            int d = kk * 32 + ko;
            bf16x8 a = *(const bf16x8*)(xr + d);
            bf16x8 w = *(const bf16x8*)(wr + d);
            acc = __builtin_amdgcn_mfma_f32_16x16x32_bf16(a, w, acc, 0, 0, 0);
        }
        int dh = dtile * 16 + mrow;
        const float* sbt = sb + ((size_t)t * DHID + dh) * GRID_SZ;
        const float* sst = ss + ((size_t)t * DHID + dh) * GRID_SZ;
        #pragma unroll
        for (int r = 0; r < 4; ++r) {
            int tr = (lane >> 4) * 4 + r;
            float h = acc[r];
            float hn = 1.f / (1.f + expf(-h));
            float g = hn * (float)GRID_SZ;
            int idx = (int)g;
            idx = idx > GRID_SZ - 1 ? GRID_SZ - 1 : idx;
            float lp = g - (float)idx;
            float val = sbt[idx] + sst[idx] * lp;
            hsl[(tr * DHID + dh) ^ ((tr & 7) << 3)] = bf16bits(val);
        }
    }
    __syncthreads();

    // ---- up: wave wv does d-slices {wv, wv+4} (4 n-tiles x 4 MFMA each) ----
    float sc_t = scale[t];
    bf16x8 a2[4];
    #pragma unroll
    for (int kk = 0; kk < 4; ++kk)
        a2[kk] = *(const bf16x8*)&hsl[(mrow * DHID + kk * 32 + ko) ^ ((mrow & 7) << 3)];
    #pragma unroll
    for (int j = 0; j < 2; ++j) {
        int sl = wv + j * 4;
        #pragma unroll
        for (int nt = 0; nt < 4; ++nt) {
            int d = sl * 64 + nt * 16 + mrow;
            const unsigned short* wru = wu_b + ((size_t)t * DIM + d) * DHID;
            f32x4 au = {0.f, 0.f, 0.f, 0.f};
            #pragma unroll
            for (int kk = 0; kk < 4; ++kk) {
                bf16x8 w = *(const bf16x8*)(wru + kk * 32 + ko);
                au = __builtin_amdgcn_mfma_f32_16x16x32_bf16(a2[kk], w, au, 0, 0, 0);
            }
            #pragma unroll
            for (int r = 0; r < 4; ++r) {
                int tr = (lane >> 4) * 4 + r;
                int tok_tr = __shfl(tokm, tr);
                if (tr < m) {
                    size_t o = (size_t)tok_tr * DIM + d;
                    out[o] = x[o] + au[r] * sc_t;
                }
            }
        }
    }
}

extern "C" void kernel_launch(void* const* d_in, const int* in_sizes, int n_in,
                              void* d_out, int out_size, void* d_ws, size_t ws_size,
                              hipStream_t stream) {
    const float* x     = (const float*)d_in[0];
    const float* gamma = (const float*)d_in[1];
    const float* beta  = (const float*)d_in[2];
    const float* Wd    = (const float*)d_in[3];
    const float* sb    = (const float*)d_in[4];
    const float* ss    = (const float*)d_in[5];
    const float* Wu    = (const float*)d_in[6];
    const float* scale = (const float*)d_in[7];
    float* out = (float*)d_out;

    // workspace layout (flags first, own 256B)
    int*   flags         = (int*)d_ws;                             // 64 ints (4 used, 64B apart)
    float* psum          = (float*)((char*)d_ws + 256);            // 64*8*512 f = 1 MB
    float* tile_sigs     = psum + (size_t)NTILES * 8 * DIM;        // 32K f
    float* cluster_sigs  = tile_sigs + NTILES * DIM;               // 4K f
    int*   counts        = (int*)(cluster_sigs + NCLUST * DIM);    // 64 ints
    int*   list          = counts + NTILES;                        // 128K ints
    unsigned short* xn_b = (unsigned short*)(list + (size_t)NTILES * NTOK);  // 1M u16
    unsigned short* wd_b = xn_b + (size_t)NTOK * DIM;              // 4.19M u16
    unsigned short* wu_b = wd_b + (size_t)NTILES * DHID * DIM;     // 4.19M u16

    hipMemsetAsync(flags, 0, 256, stream);     // zero flags each call (graph-capturable)
    k_all<<<NBLK, 256, 0, stream>>>(x, gamma, beta, Wd, sb, ss, Wu, scale, out,
                                    flags, psum, tile_sigs, cluster_sigs,
                                    counts, list, xn_b, wd_b, wu_b);
}

// Round 13
// 52.130 us; speedup vs baseline: 2.4911x; 2.4911x over previous
//
#include <hip/hip_runtime.h>
#include <hip/hip_bf16.h>
#include <math.h>

#define NTILES 64
#define TPC 8
#define NCLUST 8
#define GRID_SZ 16
#define DIM 512
#define DHID 128
#define NTOK 2048
#define LN_EPS 1e-5f
#define TB 16             // tokens per chunk == MFMA M-tile
#define NCHUNK_MAX 192    // sum ceil(cnt/16) <= 128 + 60 < 192 = 8*24

typedef __attribute__((ext_vector_type(8))) short bf16x8;
typedef __attribute__((ext_vector_type(4))) float f32x4;

static __device__ __forceinline__ float fsign(float v) {
    return (v > 0.f) ? 1.f : ((v < 0.f) ? -1.f : 0.f);
}

static __device__ __forceinline__ unsigned short bf16bits(float f) {
    union { __hip_bfloat16 h; unsigned short s; } u;
    u.h = __float2bfloat16(f);
    return u.s;
}

static __device__ __forceinline__ bf16x8 cvt8(const float* p) {
    float4 a = *(const float4*)p;
    float4 b = *(const float4*)(p + 4);
    float e[8] = {a.x, a.y, a.z, a.w, b.x, b.y, b.z, b.w};
    bf16x8 v;
    #pragma unroll
    for (int i = 0; i < 8; ++i) v[i] = (short)bf16bits(e[i]);
    return v;
}

// in-wave self-routing: chunk id cb -> (t, base, m). false if no work.
static __device__ __forceinline__ bool route_chunk(const int* counts, int lane, int cb,
                                                   int& t, int& base, int& m) {
    int cnt_l = counts[lane];
    int nck = (cnt_l + TB - 1) / TB;
    int pre = nck;
    #pragma unroll
    for (int off = 1; off < 64; off <<= 1) {
        int u = __shfl_up(pre, off);
        if (lane >= off) pre += u;
    }
    int total = __shfl(pre, 63);
    pre -= nck;
    if (cb >= total) return false;
    unsigned long long msk = __ballot(cb >= pre && cb < pre + nck);
    t = (int)__builtin_ctzll(msk);
    base = (cb - __shfl(pre, t)) * TB;
    m = min(TB, __shfl(cnt_l, t) - base);
    return true;
}

// K1: 1024 independent blocks, one dispatch (no cross-block deps):
//   0..511   : Wd column psums + bf16 Wd copy (reads each Wd element once)
//   512..1023: LayerNorm -> bf16 xn
// (Wu bf16 copy dropped: K4's up phase has slice-level MLP to hide f32 loads+cvt,
//  and the copy cost K1 ~100 MB of traffic.)
__global__ __launch_bounds__(256) void k_prep(const float* __restrict__ x,
                                              const float* __restrict__ gamma,
                                              const float* __restrict__ beta,
                                              const float* __restrict__ Wd,
                                              float* __restrict__ psum,
                                              unsigned short* __restrict__ wd_b,
                                              unsigned short* __restrict__ xn_b,
                                              int* __restrict__ counts) {
    int bid = blockIdx.x;
    int tid = threadIdx.x;
    if (bid < 512) {
        int t = bid >> 3, part = bid & 7;
        const float* basep = Wd + ((size_t)t * DHID + part * 16) * DIM;
        unsigned short* bb = wd_b + ((size_t)t * DHID + part * 16) * DIM;
        #pragma unroll
        for (int k2 = 0; k2 < 2; ++k2) {
            int d = tid + k2 * 256;
            float s = 0.f;
            #pragma unroll
            for (int j = 0; j < 16; ++j) {
                float v = basep[(size_t)j * DIM + d];
                s += v;
                bb[(size_t)j * DIM + d] = bf16bits(v);
            }
            psum[((size_t)t * 8 + part) * DIM + d] = s;
        }
        if (bid == 0 && tid < NTILES) counts[tid] = 0;
    } else {
        int n = (bid - 512) * 4 + (tid >> 6);
        int lane = tid & 63;
        const float* xr = x + (size_t)n * DIM;
        float v[8];
        float sum = 0.f;
        #pragma unroll
        for (int j = 0; j < 8; ++j) { float t = xr[lane + 64 * j]; v[j] = t; sum += t; }
        #pragma unroll
        for (int off = 32; off; off >>= 1) sum += __shfl_xor(sum, off);
        float mu = sum * (1.f / DIM);
        float sq = 0.f;
        #pragma unroll
        for (int j = 0; j < 8; ++j) { float t = v[j] - mu; sq += t * t; }
        #pragma unroll
        for (int off = 32; off; off >>= 1) sq += __shfl_xor(sq, off);
        float rs = rsqrtf(sq * (1.f / DIM) + LN_EPS);
        #pragma unroll
        for (int j = 0; j < 8; ++j) {
            int d = lane + 64 * j;
            float xv = (v[j] - mu) * rs * gamma[d] + beta[d];
            xn_b[(size_t)n * DIM + d] = bf16bits(xv);
        }
    }
}

// K2: tile_sigs + cluster_sigs. grid (NCLUST), 512 threads.
__global__ __launch_bounds__(512) void k_csig(const float* __restrict__ psum,
                                              float* __restrict__ tile_sigs,
                                              float* __restrict__ cluster_sigs) {
    int c = blockIdx.x, d = threadIdx.x;
    float csum = 0.f;
    #pragma unroll
    for (int k = 0; k < TPC; ++k) {
        int t = c * TPC + k;
        float s = 0.f;
        #pragma unroll
        for (int p = 0; p < 8; ++p) s += psum[((size_t)t * 8 + p) * DIM + d];
        float sg = fsign(s);
        tile_sigs[(size_t)t * DIM + d] = sg;
        csum += sg;
    }
    cluster_sigs[(size_t)c * DIM + d] = fsign(csum);
}

// K3: routing from bf16 xn sign bits (exact: RNE preserves sign, ±0 -> 0).
__global__ __launch_bounds__(256) void k_route(const unsigned short* __restrict__ xn_b,
                                               const float* __restrict__ tile_sigs,
                                               const float* __restrict__ cluster_sigs,
                                               int* __restrict__ counts,
                                               int* __restrict__ list) {
    int n = blockIdx.x * 4 + (threadIdx.x >> 6);
    int lane = threadIdx.x & 63;
    float sg[8];
    #pragma unroll
    for (int j = 0; j < 8; ++j) {
        unsigned short u = xn_b[(size_t)n * DIM + lane + 64 * j];
        sg[j] = ((u & 0x7fff) == 0) ? 0.f : ((u & 0x8000) ? -1.f : 1.f);
    }
    int best_c = 0; float best = -1e30f;
    for (int c = 0; c < NCLUST; ++c) {
        float s = 0.f;
        #pragma unroll
        for (int j = 0; j < 8; ++j) s += sg[j] * cluster_sigs[(size_t)c * DIM + lane + 64 * j];
        #pragma unroll
        for (int off = 32; off; off >>= 1) s += __shfl_xor(s, off);
        if (s > best) { best = s; best_c = c; }
    }
    int bt = best_c * TPC; float bts = -1e30f;
    for (int k = 0; k < TPC; ++k) {
        int t = best_c * TPC + k;
        float s = 0.f;
        #pragma unroll
        for (int j = 0; j < 8; ++j) s += sg[j] * tile_sigs[(size_t)t * DIM + lane + 64 * j];
        #pragma unroll
        for (int off = 32; off; off >>= 1) s += __shfl_xor(s, off);
        if (s > bts) { bts = s; bt = t; }
    }
    if (lane == 0) {
        int slot = atomicAdd(&counts[bt], 1);
        list[(size_t)bt * NTOK + slot] = n;
    }
}

// K4: fused down+spline+up. 192 blocks x 512 threads (8 waves, 1 chunk/block).
// down: bf16 weights (precomputed, serial K-chain benefits);
// up:   f32 Wu + inline cvt8 (nt-slice MLP hides the cvt+wider loads).
__global__ __launch_bounds__(512, 2) void k_ffn(const float* __restrict__ x,
                                                const unsigned short* __restrict__ xn_b,
                                                const unsigned short* __restrict__ wd_b,
                                                const float* __restrict__ sb,
                                                const float* __restrict__ ss,
                                                const float* __restrict__ Wu,
                                                const float* __restrict__ scale,
                                                const int* __restrict__ counts,
                                                const int* __restrict__ list,
                                                float* __restrict__ out) {
    int tid = threadIdx.x;
    int lane = tid & 63;
    int wv = tid >> 6;
    int cb = ((int)blockIdx.x & 7) * (NCHUNK_MAX / 8) + ((int)blockIdx.x >> 3);
    int t, base, m;
    if (!route_chunk(counts, lane, cb, t, base, m)) return;   // block-uniform exit

    __shared__ __align__(16) unsigned short hsl[TB * DHID];   // bf16, XOR-swizzled

    int mrow = lane & 15;
    int ko = (lane >> 4) * 8;
    int tokm = list[(size_t)t * NTOK + base + min(mrow, m - 1)];

    // ---- down: dh-tile wv (16 MFMA, K=512), pure b128-load + MFMA ----
    const unsigned short* xr = xn_b + (size_t)tokm * DIM;
    const unsigned short* wr = wd_b + ((size_t)t * DHID + wv * 16 + mrow) * DIM;
    f32x4 acc = {0.f, 0.f, 0.f, 0.f};
    #pragma unroll
    for (int kk = 0; kk < 16; ++kk) {
        int d = kk * 32 + ko;
        bf16x8 a = *(const bf16x8*)(xr + d);
        bf16x8 b = *(const bf16x8*)(wr + d);
        acc = __builtin_amdgcn_mfma_f32_16x16x32_bf16(a, b, acc, 0, 0, 0);
    }
    // spline on C fragments -> LDS (rows tr>=m hold duplicated last token: valid bytes)
    int dh = wv * 16 + mrow;
    const float* sbt = sb + ((size_t)t * DHID + dh) * GRID_SZ;
    const float* sst = ss + ((size_t)t * DHID + dh) * GRID_SZ;
    #pragma unroll
    for (int r = 0; r < 4; ++r) {
        int tr = (lane >> 4) * 4 + r;
        float h = acc[r];
        float hn = 1.f / (1.f + expf(-h));
        float g = hn * (float)GRID_SZ;
        int idx = (int)g;
        idx = idx > GRID_SZ - 1 ? GRID_SZ - 1 : idx;
        float lp = g - (float)idx;
        float val = sbt[idx] + sst[idx] * lp;
        hsl[(tr * DHID + dh) ^ ((tr & 7) << 3)] = bf16bits(val);
    }
    __syncthreads();

    // ---- up: d-slice wv (4 n-tiles x 4 MFMA, K=128), f32 Wu + cvt ----
    float sc_t = scale[t];
    bf16x8 a2[4];
    #pragma unroll
    for (int kk = 0; kk < 4; ++kk)
        a2[kk] = *(const bf16x8*)&hsl[(mrow * DHID + kk * 32 + ko) ^ ((mrow & 7) << 3)];
    #pragma unroll
    for (int nt = 0; nt < 4; ++nt) {
        int d = wv * 64 + nt * 16 + mrow;
        const float* wru = Wu + ((size_t)t * DIM + d) * DHID;
        f32x4 au = {0.f, 0.f, 0.f, 0.f};
        #pragma unroll
        for (int kk = 0; kk < 4; ++kk) {
            bf16x8 b = cvt8(wru + kk * 32 + ko);
            au = __builtin_amdgcn_mfma_f32_16x16x32_bf16(a2[kk], b, au, 0, 0, 0);
        }
        #pragma unroll
        for (int r = 0; r < 4; ++r) {
            int tr = (lane >> 4) * 4 + r;
            int tok_tr = __shfl(tokm, tr);
            if (tr < m) {
                size_t o = (size_t)tok_tr * DIM + d;
                out[o] = x[o] + au[r] * sc_t;
            }
        }
    }
}

extern "C" void kernel_launch(void* const* d_in, const int* in_sizes, int n_in,
                              void* d_out, int out_size, void* d_ws, size_t ws_size,
                              hipStream_t stream) {
    const float* x     = (const float*)d_in[0];
    const float* gamma = (const float*)d_in[1];
    const float* beta  = (const float*)d_in[2];
    const float* Wd    = (const float*)d_in[3];
    const float* sb    = (const float*)d_in[4];
    const float* ss    = (const float*)d_in[5];
    const float* Wu    = (const float*)d_in[6];
    const float* scale = (const float*)d_in[7];
    float* out = (float*)d_out;

    // workspace layout
    float* psum          = (float*)d_ws;                           // 64*8*512 f = 1 MB
    float* tile_sigs     = psum + (size_t)NTILES * 8 * DIM;        // 32K f
    float* cluster_sigs  = tile_sigs + NTILES * DIM;               // 4K f
    int*   counts        = (int*)(cluster_sigs + NCLUST * DIM);    // 64 ints
    int*   list          = counts + NTILES;                        // 128K ints
    unsigned short* xn_b = (unsigned short*)(list + (size_t)NTILES * NTOK);  // 1M u16
    unsigned short* wd_b = xn_b + (size_t)NTOK * DIM;              // 4.19M u16

    k_prep<<<1024, 256, 0, stream>>>(x, gamma, beta, Wd, psum, wd_b, xn_b, counts);
    k_csig<<<NCLUST, 512, 0, stream>>>(psum, tile_sigs, cluster_sigs);
    k_route<<<NTOK / 4, 256, 0, stream>>>(xn_b, tile_sigs, cluster_sigs, counts, list);
    k_ffn<<<NCHUNK_MAX, 512, 0, stream>>>(x, xn_b, wd_b, sb, ss, Wu, scale, counts, list, out);
}

// Round 14
// 51.376 us; speedup vs baseline: 2.5276x; 1.0147x over previous
//
#include <hip/hip_runtime.h>
#include <hip/hip_bf16.h>
#include <math.h>

#define NTILES 64
#define TPC 8
#define NCLUST 8
#define GRID_SZ 16
#define DIM 512
#define DHID 128
#define NTOK 2048
#define LN_EPS 1e-5f
#define TB 16             // tokens per chunk == MFMA M-tile
#define NCHUNK_MAX 192    // sum ceil(cnt/16) <= 128 + 60 < 192 = 8*24

typedef __attribute__((ext_vector_type(8))) short bf16x8;
typedef __attribute__((ext_vector_type(4))) float f32x4;
typedef unsigned long long u64;

static __device__ __forceinline__ unsigned short bf16bits(float f) {
    union { __hip_bfloat16 h; unsigned short s; } u;
    u.h = __float2bfloat16(f);
    return u.s;
}

static __device__ __forceinline__ bf16x8 cvt8(const float* p) {
    float4 a = *(const float4*)p;
    float4 b = *(const float4*)(p + 4);
    float e[8] = {a.x, a.y, a.z, a.w, b.x, b.y, b.z, b.w};
    bf16x8 v;
    #pragma unroll
    for (int i = 0; i < 8; ++i) v[i] = (short)bf16bits(e[i]);
    return v;
}

// in-wave self-routing: chunk id cb -> (t, base, m). false if no work.
static __device__ __forceinline__ bool route_chunk(const int* counts, int lane, int cb,
                                                   int& t, int& base, int& m) {
    int cnt_l = counts[lane];
    int nck = (cnt_l + TB - 1) / TB;
    int pre = nck;
    #pragma unroll
    for (int off = 1; off < 64; off <<= 1) {
        int u = __shfl_up(pre, off);
        if (lane >= off) pre += u;
    }
    int total = __shfl(pre, 63);
    pre -= nck;
    if (cb >= total) return false;
    u64 msk = __ballot(cb >= pre && cb < pre + nck);
    t = (int)__builtin_ctzll(msk);
    base = (cb - __shfl(pre, t)) * TB;
    m = min(TB, __shfl(cnt_l, t) - base);
    return true;
}

// K1: 1024 independent blocks:
//   0..511   : Wd column psums + bf16 Wd copy
//   512..1023: LayerNorm -> bf16 xn
__global__ __launch_bounds__(256) void k_prep(const float* __restrict__ x,
                                              const float* __restrict__ gamma,
                                              const float* __restrict__ beta,
                                              const float* __restrict__ Wd,
                                              float* __restrict__ psum,
                                              unsigned short* __restrict__ wd_b,
                                              unsigned short* __restrict__ xn_b,
                                              int* __restrict__ counts) {
    int bid = blockIdx.x;
    int tid = threadIdx.x;
    if (bid < 512) {
        int t = bid >> 3, part = bid & 7;
        const float* basep = Wd + ((size_t)t * DHID + part * 16) * DIM;
        unsigned short* bb = wd_b + ((size_t)t * DHID + part * 16) * DIM;
        #pragma unroll
        for (int k2 = 0; k2 < 2; ++k2) {
            int d = tid + k2 * 256;
            float s = 0.f;
            #pragma unroll
            for (int j = 0; j < 16; ++j) {
                float v = basep[(size_t)j * DIM + d];
                s += v;
                bb[(size_t)j * DIM + d] = bf16bits(v);
            }
            psum[((size_t)t * 8 + part) * DIM + d] = s;
        }
        if (bid == 0 && tid < NTILES) counts[tid] = 0;
    } else {
        int n = (bid - 512) * 4 + (tid >> 6);
        int lane = tid & 63;
        const float* xr = x + (size_t)n * DIM;
        float v[8];
        float sum = 0.f;
        #pragma unroll
        for (int j = 0; j < 8; ++j) { float t = xr[lane + 64 * j]; v[j] = t; sum += t; }
        #pragma unroll
        for (int off = 32; off; off >>= 1) sum += __shfl_xor(sum, off);
        float mu = sum * (1.f / DIM);
        float sq = 0.f;
        #pragma unroll
        for (int j = 0; j < 8; ++j) { float t = v[j] - mu; sq += t * t; }
        #pragma unroll
        for (int off = 32; off; off >>= 1) sq += __shfl_xor(sq, off);
        float rs = rsqrtf(sq * (1.f / DIM) + LN_EPS);
        #pragma unroll
        for (int j = 0; j < 8; ++j) {
            int d = lane + 64 * j;
            float xv = (v[j] - mu) * rs * gamma[d] + beta[d];
            xn_b[(size_t)n * DIM + d] = bf16bits(xv);
        }
    }
}

// K2: bitpacked signatures. 8 blocks x 512 threads (wave w = tile w of cluster).
// tbits[t][j] bit l = (tile_sig[t][l+64j] < 0). cbits/cmask: cluster sign / nonzero.
__global__ __launch_bounds__(512) void k_csig(const float* __restrict__ psum,
                                              u64* __restrict__ tbits,
                                              u64* __restrict__ cbits,
                                              u64* __restrict__ cmask) {
    int c = blockIdx.x;
    int w = threadIdx.x >> 6;
    int lane = threadIdx.x & 63;
    int t = c * TPC + w;
    __shared__ u64 tb_lds[TPC][8];
    #pragma unroll
    for (int j = 0; j < 8; ++j) {
        int d = lane + 64 * j;
        float s = 0.f;
        #pragma unroll
        for (int p = 0; p < 8; ++p) s += psum[((size_t)t * 8 + p) * DIM + d];
        u64 b = __ballot(s < 0.f);
        if (lane == 0) { tbits[t * 8 + j] = b; tb_lds[w][j] = b; }
    }
    __syncthreads();
    // wave w computes cluster word j=w: csum[d] = 8 - 2*cnt_neg
    int cnt = 0;
    #pragma unroll
    for (int k = 0; k < TPC; ++k) cnt += (int)((tb_lds[k][w] >> lane) & 1ULL);
    u64 cb = __ballot(cnt > 4);     // negative
    u64 cm = __ballot(cnt != 4);    // nonzero
    if (lane == 0) { cbits[c * 8 + w] = cb; cmask[c * 8 + w] = cm; }
}

// K3: bitpacked routing, one token per wave. Integer scores == exact f32 argmax.
// (xn exactly ±0 would differ from ref sign(0)=0 by ±1 per elem - measure-zero for
//  random normal inputs; bf16-sign routing has passed since R10.)
__global__ __launch_bounds__(256) void k_route(const unsigned short* __restrict__ xn_b,
                                               const u64* __restrict__ tbits,
                                               const u64* __restrict__ cbits,
                                               const u64* __restrict__ cmask,
                                               int* __restrict__ counts,
                                               int* __restrict__ list) {
    int n = blockIdx.x * 4 + (threadIdx.x >> 6);
    int lane = threadIdx.x & 63;
    u64 xb[8];
    #pragma unroll
    for (int j = 0; j < 8; ++j) {
        unsigned short u = xn_b[(size_t)n * DIM + lane + 64 * j];
        xb[j] = __ballot((u & 0x8000u) != 0 && (u & 0x7fffu) != 0);  // strictly negative
    }
    // per-lane tile score: tile = lane
    const u64* tb = tbits + lane * 8;
    int ts = 0;
    #pragma unroll
    for (int j = 0; j < 8; ++j) ts += __popcll(xb[j] ^ tb[j]);
    int tscore = DIM - 2 * ts;
    // cluster score on lanes 0..7 (masked for zero cluster-sigs)
    int cscore = -(1 << 30);
    if (lane < NCLUST) {
        const u64* cb = cbits + lane * 8;
        const u64* cm = cmask + lane * 8;
        int s = 0;
        #pragma unroll
        for (int j = 0; j < 8; ++j)
            s += __popcll(cm[j]) - 2 * __popcll((xb[j] ^ cb[j]) & cm[j]);
        cscore = s;
    }
    // argmax cluster (first-index tie-break), then tile within cluster
    int bc = 0, best = __shfl(cscore, 0);
    #pragma unroll
    for (int k = 1; k < NCLUST; ++k) {
        int v = __shfl(cscore, k);
        if (v > best) { best = v; bc = k; }
    }
    int bt = bc * TPC, bts = __shfl(tscore, bc * TPC);
    #pragma unroll
    for (int k = 1; k < TPC; ++k) {
        int v = __shfl(tscore, bc * TPC + k);
        if (v > bts) { bts = v; bt = bc * TPC + k; }
    }
    if (lane == 0) {
        int slot = atomicAdd(&counts[bt], 1);
        list[(size_t)bt * NTOK + slot] = n;
    }
}

// K4: fused down+spline+up. 192 blocks x 512 threads (8 waves, 1 chunk/block).
// down: bf16 weights, DUAL accumulator (2x8 MFMA chains); up: f32 Wu + inline cvt.
__global__ __launch_bounds__(512, 2) void k_ffn(const float* __restrict__ x,
                                                const unsigned short* __restrict__ xn_b,
                                                const unsigned short* __restrict__ wd_b,
                                                const float* __restrict__ sb,
                                                const float* __restrict__ ss,
                                                const float* __restrict__ Wu,
                                                const float* __restrict__ scale,
                                                const int* __restrict__ counts,
                                                const int* __restrict__ list,
                                                float* __restrict__ out) {
    int tid = threadIdx.x;
    int lane = tid & 63;
    int wv = tid >> 6;
    int cb = ((int)blockIdx.x & 7) * (NCHUNK_MAX / 8) + ((int)blockIdx.x >> 3);
    int t, base, m;
    if (!route_chunk(counts, lane, cb, t, base, m)) return;   // block-uniform exit

    __shared__ __align__(16) unsigned short hsl[TB * DHID];   // bf16, XOR-swizzled

    int mrow = lane & 15;
    int ko = (lane >> 4) * 8;
    int tokm = list[(size_t)t * NTOK + base + min(mrow, m - 1)];

    // ---- down: dh-tile wv, two independent 8-MFMA chains ----
    const unsigned short* xr = xn_b + (size_t)tokm * DIM;
    const unsigned short* wr = wd_b + ((size_t)t * DHID + wv * 16 + mrow) * DIM;
    f32x4 acc0 = {0.f, 0.f, 0.f, 0.f}, acc1 = acc0;
    #pragma unroll
    for (int kk = 0; kk < 8; ++kk) {
        int d0 = kk * 32 + ko;
        int d1 = (kk + 8) * 32 + ko;
        bf16x8 a0 = *(const bf16x8*)(xr + d0);
        bf16x8 b0 = *(const bf16x8*)(wr + d0);
        acc0 = __builtin_amdgcn_mfma_f32_16x16x32_bf16(a0, b0, acc0, 0, 0, 0);
        bf16x8 a1 = *(const bf16x8*)(xr + d1);
        bf16x8 b1 = *(const bf16x8*)(wr + d1);
        acc1 = __builtin_amdgcn_mfma_f32_16x16x32_bf16(a1, b1, acc1, 0, 0, 0);
    }
    f32x4 acc = acc0 + acc1;
    // spline on C fragments -> LDS (rows tr>=m hold duplicated last token: valid bytes)
    int dh = wv * 16 + mrow;
    const float* sbt = sb + ((size_t)t * DHID + dh) * GRID_SZ;
    const float* sst = ss + ((size_t)t * DHID + dh) * GRID_SZ;
    #pragma unroll
    for (int r = 0; r < 4; ++r) {
        int tr = (lane >> 4) * 4 + r;
        float h = acc[r];
        float hn = 1.f / (1.f + expf(-h));
        float g = hn * (float)GRID_SZ;
        int idx = (int)g;
        idx = idx > GRID_SZ - 1 ? GRID_SZ - 1 : idx;
        float lp = g - (float)idx;
        float val = sbt[idx] + sst[idx] * lp;
        hsl[(tr * DHID + dh) ^ ((tr & 7) << 3)] = bf16bits(val);
    }
    __syncthreads();

    // ---- up: d-slice wv (4 independent n-tiles x 4 MFMA, K=128) ----
    float sc_t = scale[t];
    bf16x8 a2[4];
    #pragma unroll
    for (int kk = 0; kk < 4; ++kk)
        a2[kk] = *(const bf16x8*)&hsl[(mrow * DHID + kk * 32 + ko) ^ ((mrow & 7) << 3)];
    #pragma unroll
    for (int nt = 0; nt < 4; ++nt) {
        int d = wv * 64 + nt * 16 + mrow;
        const float* wru = Wu + ((size_t)t * DIM + d) * DHID;
        f32x4 au = {0.f, 0.f, 0.f, 0.f};
        #pragma unroll
        for (int kk = 0; kk < 4; ++kk) {
            bf16x8 b = cvt8(wru + kk * 32 + ko);
            au = __builtin_amdgcn_mfma_f32_16x16x32_bf16(a2[kk], b, au, 0, 0, 0);
        }
        #pragma unroll
        for (int r = 0; r < 4; ++r) {
            int tr = (lane >> 4) * 4 + r;
            int tok_tr = __shfl(tokm, tr);
            if (tr < m) {
                size_t o = (size_t)tok_tr * DIM + d;
                out[o] = x[o] + au[r] * sc_t;
            }
        }
    }
}

extern "C" void kernel_launch(void* const* d_in, const int* in_sizes, int n_in,
                              void* d_out, int out_size, void* d_ws, size_t ws_size,
                              hipStream_t stream) {
    const float* x     = (const float*)d_in[0];
    const float* gamma = (const float*)d_in[1];
    const float* beta  = (const float*)d_in[2];
    const float* Wd    = (const float*)d_in[3];
    const float* sb    = (const float*)d_in[4];
    const float* ss    = (const float*)d_in[5];
    const float* Wu    = (const float*)d_in[6];
    const float* scale = (const float*)d_in[7];
    float* out = (float*)d_out;

    // workspace layout
    float* psum          = (float*)d_ws;                           // 64*8*512 f = 1 MB
    u64*   tbits         = (u64*)(psum + (size_t)NTILES * 8 * DIM);// 64*8 u64 = 4 KB
    u64*   cbits         = tbits + NTILES * 8;                     // 8*8 u64
    u64*   cmask         = cbits + NCLUST * 8;                     // 8*8 u64
    int*   counts        = (int*)(cmask + NCLUST * 8);             // 64 ints
    int*   list          = counts + NTILES;                        // 128K ints
    unsigned short* xn_b = (unsigned short*)(list + (size_t)NTILES * NTOK);  // 1M u16
    unsigned short* wd_b = xn_b + (size_t)NTOK * DIM;              // 4.19M u16

    k_prep<<<1024, 256, 0, stream>>>(x, gamma, beta, Wd, psum, wd_b, xn_b, counts);
    k_csig<<<NCLUST, 512, 0, stream>>>(psum, tbits, cbits, cmask);
    k_route<<<NTOK / 4, 256, 0, stream>>>(xn_b, tbits, cbits, cmask, counts, list);
    k_ffn<<<NCHUNK_MAX, 512, 0, stream>>>(x, xn_b, wd_b, sb, ss, Wu, scale, counts, list, out);
}

// Round 15
// 50.491 us; speedup vs baseline: 2.5719x; 1.0175x over previous
//
#include <hip/hip_runtime.h>
#include <hip/hip_bf16.h>
#include <math.h>

#define NTILES 64
#define TPC 8
#define NCLUST 8
#define GRID_SZ 16
#define DIM 512
#define DHID 128
#define NTOK 2048
#define LN_EPS 1e-5f
#define TB 16             // tokens per chunk == MFMA M-tile
#define NCHUNK_MAX 192    // sum ceil(cnt/16) <= 128 + 60 < 192 = 8*24

typedef __attribute__((ext_vector_type(8))) short bf16x8;
typedef __attribute__((ext_vector_type(4))) float f32x4;
typedef unsigned long long u64;

static __device__ __forceinline__ unsigned short bf16bits(float f) {
    union { __hip_bfloat16 h; unsigned short s; } u;
    u.h = __float2bfloat16(f);
    return u.s;
}

static __device__ __forceinline__ bf16x8 cvt8v(float4 a, float4 b) {
    float e[8] = {a.x, a.y, a.z, a.w, b.x, b.y, b.z, b.w};
    bf16x8 v;
    #pragma unroll
    for (int i = 0; i < 8; ++i) v[i] = (short)bf16bits(e[i]);
    return v;
}

static __device__ __forceinline__ bf16x8 cvt8(const float* p) {
    return cvt8v(*(const float4*)p, *(const float4*)(p + 4));
}

static __device__ __forceinline__ u64 maj3(u64 a, u64 b, u64 c) {
    return (a & b) | (c & (a ^ b));
}

// in-wave self-routing: chunk id cb -> (t, base, m). false if no work.
static __device__ __forceinline__ bool route_chunk(const int* counts, int lane, int cb,
                                                   int& t, int& base, int& m) {
    int cnt_l = counts[lane];
    int nck = (cnt_l + TB - 1) / TB;
    int pre = nck;
    #pragma unroll
    for (int off = 1; off < 64; off <<= 1) {
        int u = __shfl_up(pre, off);
        if (lane >= off) pre += u;
    }
    int total = __shfl(pre, 63);
    pre -= nck;
    if (cb >= total) return false;
    u64 msk = __ballot(cb >= pre && cb < pre + nck);
    t = (int)__builtin_ctzll(msk);
    base = (cb - __shfl(pre, t)) * TB;
    m = min(TB, __shfl(cnt_l, t) - base);
    return true;
}

// K1: 320 independent blocks x 512 threads:
//   0..63  : tile t full column sums (+bf16 Wd copy) -> tbits via ballot
//   64..319: LayerNorm (8 tokens/block) -> bf16 xn
__global__ __launch_bounds__(512) void k_prep(const float* __restrict__ x,
                                              const float* __restrict__ gamma,
                                              const float* __restrict__ beta,
                                              const float* __restrict__ Wd,
                                              unsigned short* __restrict__ wd_b,
                                              unsigned short* __restrict__ xn_b,
                                              u64* __restrict__ tbits,
                                              int* __restrict__ counts) {
    int bid = blockIdx.x;
    int tid = threadIdx.x;
    int lane = tid & 63;
    int wv = tid >> 6;
    if (bid < NTILES) {
        int t = bid;
        if (bid == 0 && tid < NTILES) counts[tid] = 0;
        const float* bp = Wd + (size_t)t * DHID * DIM + tid;
        unsigned short* bb = wd_b + (size_t)t * DHID * DIM + tid;
        float s0 = 0.f, s1 = 0.f, s2 = 0.f, s3 = 0.f;
        #pragma unroll 4
        for (int j = 0; j < DHID; j += 4) {
            float v0 = bp[(size_t)(j + 0) * DIM];
            float v1 = bp[(size_t)(j + 1) * DIM];
            float v2 = bp[(size_t)(j + 2) * DIM];
            float v3 = bp[(size_t)(j + 3) * DIM];
            bb[(size_t)(j + 0) * DIM] = bf16bits(v0);
            bb[(size_t)(j + 1) * DIM] = bf16bits(v1);
            bb[(size_t)(j + 2) * DIM] = bf16bits(v2);
            bb[(size_t)(j + 3) * DIM] = bf16bits(v3);
            s0 += v0; s1 += v1; s2 += v2; s3 += v3;
        }
        float s = (s0 + s1) + (s2 + s3);
        u64 b = __ballot(s < 0.f);          // word wv covers columns wv*64+lane
        if (lane == 0) tbits[t * 8 + wv] = b;
    } else {
        int n = (bid - NTILES) * 8 + wv;
        const float* xr = x + (size_t)n * DIM;
        float v[8];
        float sum = 0.f;
        #pragma unroll
        for (int j = 0; j < 8; ++j) { float t = xr[lane + 64 * j]; v[j] = t; sum += t; }
        #pragma unroll
        for (int off = 32; off; off >>= 1) sum += __shfl_xor(sum, off);
        float mu = sum * (1.f / DIM);
        float sq = 0.f;
        #pragma unroll
        for (int j = 0; j < 8; ++j) { float t = v[j] - mu; sq += t * t; }
        #pragma unroll
        for (int off = 32; off; off >>= 1) sq += __shfl_xor(sq, off);
        float rs = rsqrtf(sq * (1.f / DIM) + LN_EPS);
        #pragma unroll
        for (int j = 0; j < 8; ++j) {
            int d = lane + 64 * j;
            float xv = (v[j] - mu) * rs * gamma[d] + beta[d];
            xn_b[(size_t)n * DIM + d] = bf16bits(xv);
        }
    }
}

// K2: routing, one token per wave. Cluster majority bits computed inline from tbits
// via bitwise CSA (lane k handles cluster k>>3, word k&7). Integer scores == exact
// f32 argmax with first-index tie-break.
__global__ __launch_bounds__(256) void k_route(const unsigned short* __restrict__ xn_b,
                                               const u64* __restrict__ tbits,
                                               int* __restrict__ counts,
                                               int* __restrict__ list) {
    int n = blockIdx.x * 4 + (threadIdx.x >> 6);
    int lane = threadIdx.x & 63;
    u64 xb[8];
    #pragma unroll
    for (int j = 0; j < 8; ++j) {
        unsigned short u = xn_b[(size_t)n * DIM + lane + 64 * j];
        xb[j] = __ballot((u & 0x8000u) != 0 && (u & 0x7fffu) != 0);  // strictly negative
    }
    // tile score: tile = lane
    const u64* tb = tbits + lane * 8;
    int ts = 0;
    #pragma unroll
    for (int j = 0; j < 8; ++j) ts += __popcll(xb[j] ^ tb[j]);
    int tscore = DIM - 2 * ts;

    // cluster bits: lane k -> (c = k>>3, j = k&7); majority over 8 tile words
    int c = lane >> 3, jw = lane & 7;
    u64 x0 = tbits[(c * TPC + 0) * 8 + jw], x1 = tbits[(c * TPC + 1) * 8 + jw];
    u64 x2 = tbits[(c * TPC + 2) * 8 + jw], x3 = tbits[(c * TPC + 3) * 8 + jw];
    u64 x4 = tbits[(c * TPC + 4) * 8 + jw], x5 = tbits[(c * TPC + 5) * 8 + jw];
    u64 x6 = tbits[(c * TPC + 6) * 8 + jw], x7 = tbits[(c * TPC + 7) * 8 + jw];
    u64 s0 = x0 ^ x1 ^ x2, c0 = maj3(x0, x1, x2);
    u64 s1 = x3 ^ x4 ^ x5, c1 = maj3(x3, x4, x5);
    u64 s2 = x6 ^ x7,      c2 = x6 & x7;
    u64 t0 = s0 ^ s1 ^ s2, t1 = maj3(s0, s1, s2);
    // cnt = t0 + 2*(c0+c1+c2+t1); S = c0+c1+c2+t1 = 2*(q+s_+car)+S0
    u64 p = c0 ^ c1, q = c0 & c1;
    u64 r = c2 ^ t1, s_ = c2 & t1;
    u64 S0 = p ^ r, car = p & r;
    u64 W0 = (q ^ s_) ^ car;
    u64 W1 = (q & s_) | (car & (q ^ s_));
    u64 cbit = W1 | (W0 & (S0 | t0));                 // cnt_neg > 4  -> sign -1
    u64 cmsk = ~(W0 & ~W1 & ~S0 & ~t0);               // cnt_neg != 4 -> nonzero
    int ps = __popcll(cmsk) - 2 * __popcll((xb[jw] ^ cbit) & cmsk);
    ps += __shfl_xor(ps, 1);
    ps += __shfl_xor(ps, 2);
    ps += __shfl_xor(ps, 4);                           // all lanes of 8-group: cscore(c)

    int bc = 0, best = __shfl(ps, 0);
    #pragma unroll
    for (int k = 1; k < NCLUST; ++k) {
        int v = __shfl(ps, k * 8);
        if (v > best) { best = v; bc = k; }
    }
    int bt = bc * TPC, bts = __shfl(tscore, bc * TPC);
    #pragma unroll
    for (int k = 1; k < TPC; ++k) {
        int v = __shfl(tscore, bc * TPC + k);
        if (v > bts) { bts = v; bt = bc * TPC + k; }
    }
    if (lane == 0) {
        int slot = atomicAdd(&counts[bt], 1);
        list[(size_t)bt * NTOK + slot] = n;
    }
}

// K3: fused down+spline+up. 192 blocks x 512 threads (8 waves, 1 chunk/block).
// down: bf16 weights, dual 8-MFMA chains; up: f32 Wu + inline cvt, nt=0 prefetched
// before the barrier so its latency hides under spline+sync.
__global__ __launch_bounds__(512, 2) void k_ffn(const float* __restrict__ x,
                                                const unsigned short* __restrict__ xn_b,
                                                const unsigned short* __restrict__ wd_b,
                                                const float* __restrict__ sb,
                                                const float* __restrict__ ss,
                                                const float* __restrict__ Wu,
                                                const float* __restrict__ scale,
                                                const int* __restrict__ counts,
                                                const int* __restrict__ list,
                                                float* __restrict__ out) {
    int tid = threadIdx.x;
    int lane = tid & 63;
    int wv = tid >> 6;
    int cb = ((int)blockIdx.x & 7) * (NCHUNK_MAX / 8) + ((int)blockIdx.x >> 3);
    int t, base, m;
    if (!route_chunk(counts, lane, cb, t, base, m)) return;   // block-uniform exit

    __shared__ __align__(16) unsigned short hsl[TB * DHID];   // bf16, XOR-swizzled

    int mrow = lane & 15;
    int ko = (lane >> 4) * 8;
    int tokm = list[(size_t)t * NTOK + base + min(mrow, m - 1)];

    // ---- down: dh-tile wv, two independent 8-MFMA chains ----
    const unsigned short* xr = xn_b + (size_t)tokm * DIM;
    const unsigned short* wr = wd_b + ((size_t)t * DHID + wv * 16 + mrow) * DIM;
    f32x4 acc0 = {0.f, 0.f, 0.f, 0.f}, acc1 = acc0;
    #pragma unroll
    for (int kk = 0; kk < 8; ++kk) {
        int d0 = kk * 32 + ko;
        int d1 = (kk + 8) * 32 + ko;
        bf16x8 a0 = *(const bf16x8*)(xr + d0);
        bf16x8 b0 = *(const bf16x8*)(wr + d0);
        acc0 = __builtin_amdgcn_mfma_f32_16x16x32_bf16(a0, b0, acc0, 0, 0, 0);
        bf16x8 a1 = *(const bf16x8*)(xr + d1);
        bf16x8 b1 = *(const bf16x8*)(wr + d1);
        acc1 = __builtin_amdgcn_mfma_f32_16x16x32_bf16(a1, b1, acc1, 0, 0, 0);
    }
    f32x4 acc = acc0 + acc1;

    // prefetch up-phase nt=0 Wu rows (independent of spline; issued before barrier)
    const float* wru0 = Wu + ((size_t)t * DIM + wv * 64 + mrow) * DHID;
    float4 pfa[4], pfb[4];
    #pragma unroll
    for (int kk = 0; kk < 4; ++kk) {
        pfa[kk] = *(const float4*)(wru0 + kk * 32 + ko);
        pfb[kk] = *(const float4*)(wru0 + kk * 32 + ko + 4);
    }

    // spline on C fragments -> LDS (rows tr>=m hold duplicated last token: valid bytes)
    int dh = wv * 16 + mrow;
    const float* sbt = sb + ((size_t)t * DHID + dh) * GRID_SZ;
    const float* sst = ss + ((size_t)t * DHID + dh) * GRID_SZ;
    #pragma unroll
    for (int r = 0; r < 4; ++r) {
        int tr = (lane >> 4) * 4 + r;
        float h = acc[r];
        float hn = 1.f / (1.f + expf(-h));
        float g = hn * (float)GRID_SZ;
        int idx = (int)g;
        idx = idx > GRID_SZ - 1 ? GRID_SZ - 1 : idx;
        float lp = g - (float)idx;
        float val = sbt[idx] + sst[idx] * lp;
        hsl[(tr * DHID + dh) ^ ((tr & 7) << 3)] = bf16bits(val);
    }
    __syncthreads();

    // ---- up: d-slice wv (4 independent n-tiles x 4 MFMA, K=128) ----
    float sc_t = scale[t];
    bf16x8 a2[4];
    #pragma unroll
    for (int kk = 0; kk < 4; ++kk)
        a2[kk] = *(const bf16x8*)&hsl[(mrow * DHID + kk * 32 + ko) ^ ((mrow & 7) << 3)];
    #pragma unroll
    for (int nt = 0; nt < 4; ++nt) {
        int d = wv * 64 + nt * 16 + mrow;
        const float* wru = Wu + ((size_t)t * DIM + d) * DHID;
        f32x4 au = {0.f, 0.f, 0.f, 0.f};
        #pragma unroll
        for (int kk = 0; kk < 4; ++kk) {
            bf16x8 b = (nt == 0) ? cvt8v(pfa[kk], pfb[kk])
                                 : cvt8(wru + kk * 32 + ko);
            au = __builtin_amdgcn_mfma_f32_16x16x32_bf16(a2[kk], b, au, 0, 0, 0);
        }
        #pragma unroll
        for (int r = 0; r < 4; ++r) {
            int tr = (lane >> 4) * 4 + r;
            int tok_tr = __shfl(tokm, tr);
            if (tr < m) {
                size_t o = (size_t)tok_tr * DIM + d;
                out[o] = x[o] + au[r] * sc_t;
            }
        }
    }
}

extern "C" void kernel_launch(void* const* d_in, const int* in_sizes, int n_in,
                              void* d_out, int out_size, void* d_ws, size_t ws_size,
                              hipStream_t stream) {
    const float* x     = (const float*)d_in[0];
    const float* gamma = (const float*)d_in[1];
    const float* beta  = (const float*)d_in[2];
    const float* Wd    = (const float*)d_in[3];
    const float* sb    = (const float*)d_in[4];
    const float* ss    = (const float*)d_in[5];
    const float* Wu    = (const float*)d_in[6];
    const float* scale = (const float*)d_in[7];
    float* out = (float*)d_out;

    // workspace layout
    u64*   tbits         = (u64*)d_ws;                             // 64*8 u64 = 4 KB
    int*   counts        = (int*)(tbits + NTILES * 8);             // 64 ints
    int*   list          = counts + NTILES;                        // 128K ints
    unsigned short* xn_b = (unsigned short*)(list + (size_t)NTILES * NTOK);  // 1M u16
    unsigned short* wd_b = xn_b + (size_t)NTOK * DIM;              // 4.19M u16

    k_prep<<<NTILES + NTOK / 8, 512, 0, stream>>>(x, gamma, beta, Wd, wd_b, xn_b, tbits, counts);
    k_route<<<NTOK / 4, 256, 0, stream>>>(xn_b, tbits, counts, list);
    k_ffn<<<NCHUNK_MAX, 512, 0, stream>>>(x, xn_b, wd_b, sb, ss, Wu, scale, counts, list, out);
}

// Round 16
// 45.506 us; speedup vs baseline: 2.8537x; 1.1096x over previous
//
#include <hip/hip_runtime.h>
#include <hip/hip_bf16.h>
#include <math.h>

#define NTILES 64
#define TPC 8
#define NCLUST 8
#define GRID_SZ 16
#define DIM 512
#define DHID 128
#define NTOK 2048
#define LN_EPS 1e-5f
#define TB 16             // tokens per chunk == MFMA M-tile
#define NCHUNK_MAX 192    // sum ceil(cnt/16) <= 128 + 60 < 192 = 8*24

typedef __attribute__((ext_vector_type(8))) short bf16x8;
typedef __attribute__((ext_vector_type(4))) unsigned short u16x4;
typedef __attribute__((ext_vector_type(4))) float f32x4;
typedef unsigned long long u64;

static __device__ __forceinline__ unsigned short bf16bits(float f) {
    union { __hip_bfloat16 h; unsigned short s; } u;
    u.h = __float2bfloat16(f);
    return u.s;
}

static __device__ __forceinline__ bf16x8 cvt8(const float* p) {
    float4 a = *(const float4*)p;
    float4 b = *(const float4*)(p + 4);
    float e[8] = {a.x, a.y, a.z, a.w, b.x, b.y, b.z, b.w};
    bf16x8 v;
    #pragma unroll
    for (int i = 0; i < 8; ++i) v[i] = (short)bf16bits(e[i]);
    return v;
}

static __device__ __forceinline__ u64 maj3(u64 a, u64 b, u64 c) {
    return (a & b) | (c & (a ^ b));
}

// in-wave self-routing: chunk id cb -> (t, base, m). false if no work.
static __device__ __forceinline__ bool route_chunk(const int* counts, int lane, int cb,
                                                   int& t, int& base, int& m) {
    int cnt_l = counts[lane];
    int nck = (cnt_l + TB - 1) / TB;
    int pre = nck;
    #pragma unroll
    for (int off = 1; off < 64; off <<= 1) {
        int u = __shfl_up(pre, off);
        if (lane >= off) pre += u;
    }
    int total = __shfl(pre, 63);
    pre -= nck;
    if (cb >= total) return false;
    u64 msk = __ballot(cb >= pre && cb < pre + nck);
    t = (int)__builtin_ctzll(msk);
    base = (cb - __shfl(pre, t)) * TB;
    m = min(TB, __shfl(cnt_l, t) - base);
    return true;
}

// K1: 576 independent blocks x 512 threads (all cold-HBM bytes stream here):
//   0..63   : tile t column sums via float4 (+bf16 Wd copy) -> tbits via ballot
//   64..319 : LayerNorm (8 tokens/block) -> bf16 xn
//   320..575: Wu -> bf16 streaming copy
__global__ __launch_bounds__(512) void k_prep(const float* __restrict__ x,
                                              const float* __restrict__ gamma,
                                              const float* __restrict__ beta,
                                              const float* __restrict__ Wd,
                                              const float* __restrict__ Wu,
                                              unsigned short* __restrict__ wd_b,
                                              unsigned short* __restrict__ wu_b,
                                              unsigned short* __restrict__ xn_b,
                                              u64* __restrict__ tbits,
                                              int* __restrict__ counts) {
    int bid = blockIdx.x;
    int tid = threadIdx.x;
    int lane = tid & 63;
    int wv = tid >> 6;
    if (bid < NTILES) {
        int t = bid;
        if (bid == 0 && tid < NTILES) counts[tid] = 0;
        int q = tid >> 7;          // row quarter 0..3 (rows q*32 .. q*32+31)
        int c4 = tid & 127;        // col group (cols c4*4 .. c4*4+3)
        const float* wp = Wd + ((size_t)t * DHID + q * 32) * DIM + c4 * 4;
        unsigned short* bp = wd_b + ((size_t)t * DHID + q * 32) * DIM + c4 * 4;
        float4 a = {0.f, 0.f, 0.f, 0.f};
        #pragma unroll
        for (int j = 0; j < 32; ++j) {
            float4 v = *(const float4*)(wp + (size_t)j * DIM);
            u16x4 h = {bf16bits(v.x), bf16bits(v.y), bf16bits(v.z), bf16bits(v.w)};
            *(u16x4*)(bp + (size_t)j * DIM) = h;
            a.x += v.x; a.y += v.y; a.z += v.z; a.w += v.w;
        }
        __shared__ float ps[4][DIM];
        *(float4*)&ps[q][c4 * 4] = a;
        __syncthreads();
        float s = ps[0][tid] + ps[1][tid] + ps[2][tid] + ps[3][tid];
        u64 b = __ballot(s < 0.f);       // word wv covers columns wv*64+lane
        if (lane == 0) tbits[t * 8 + wv] = b;
    } else if (bid < 320) {
        int n = (bid - NTILES) * 8 + wv;
        const float* xr = x + (size_t)n * DIM;
        float v[8];
        float sum = 0.f;
        #pragma unroll
        for (int j = 0; j < 8; ++j) { float t = xr[lane + 64 * j]; v[j] = t; sum += t; }
        #pragma unroll
        for (int off = 32; off; off >>= 1) sum += __shfl_xor(sum, off);
        float mu = sum * (1.f / DIM);
        float sq = 0.f;
        #pragma unroll
        for (int j = 0; j < 8; ++j) { float t = v[j] - mu; sq += t * t; }
        #pragma unroll
        for (int off = 32; off; off >>= 1) sq += __shfl_xor(sq, off);
        float rs = rsqrtf(sq * (1.f / DIM) + LN_EPS);
        #pragma unroll
        for (int j = 0; j < 8; ++j) {
            int d = lane + 64 * j;
            float xv = (v[j] - mu) * rs * gamma[d] + beta[d];
            xn_b[(size_t)n * DIM + d] = bf16bits(xv);
        }
    } else {
        // Wu streaming cvt: 256 blocks x 16384 floats
        size_t basei = (size_t)(bid - 320) * 16384;
        #pragma unroll
        for (int k = 0; k < 4; ++k) {
            size_t off = basei + (size_t)tid * 8 + (size_t)k * 4096;
            *(bf16x8*)(wu_b + off) = cvt8(Wu + off);
        }
    }
}

// K2: routing, one token per wave. Cluster majority bits computed inline from tbits
// via bitwise CSA (lane k handles cluster k>>3, word k&7). Integer scores == exact
// f32 argmax with first-index tie-break.
__global__ __launch_bounds__(256) void k_route(const unsigned short* __restrict__ xn_b,
                                               const u64* __restrict__ tbits,
                                               int* __restrict__ counts,
                                               int* __restrict__ list) {
    int n = blockIdx.x * 4 + (threadIdx.x >> 6);
    int lane = threadIdx.x & 63;
    u64 xb[8];
    #pragma unroll
    for (int j = 0; j < 8; ++j) {
        unsigned short u = xn_b[(size_t)n * DIM + lane + 64 * j];
        xb[j] = __ballot((u & 0x8000u) != 0 && (u & 0x7fffu) != 0);  // strictly negative
    }
    const u64* tb = tbits + lane * 8;
    int ts = 0;
    #pragma unroll
    for (int j = 0; j < 8; ++j) ts += __popcll(xb[j] ^ tb[j]);
    int tscore = DIM - 2 * ts;

    int c = lane >> 3, jw = lane & 7;
    u64 x0 = tbits[(c * TPC + 0) * 8 + jw], x1 = tbits[(c * TPC + 1) * 8 + jw];
    u64 x2 = tbits[(c * TPC + 2) * 8 + jw], x3 = tbits[(c * TPC + 3) * 8 + jw];
    u64 x4 = tbits[(c * TPC + 4) * 8 + jw], x5 = tbits[(c * TPC + 5) * 8 + jw];
    u64 x6 = tbits[(c * TPC + 6) * 8 + jw], x7 = tbits[(c * TPC + 7) * 8 + jw];
    u64 s0 = x0 ^ x1 ^ x2, c0 = maj3(x0, x1, x2);
    u64 s1 = x3 ^ x4 ^ x5, c1 = maj3(x3, x4, x5);
    u64 s2 = x6 ^ x7,      c2 = x6 & x7;
    u64 t0 = s0 ^ s1 ^ s2, t1 = maj3(s0, s1, s2);
    u64 p = c0 ^ c1, q = c0 & c1;
    u64 r = c2 ^ t1, s_ = c2 & t1;
    u64 S0 = p ^ r, car = p & r;
    u64 W0 = (q ^ s_) ^ car;
    u64 W1 = (q & s_) | (car & (q ^ s_));
    u64 cbit = W1 | (W0 & (S0 | t0));
    u64 cmsk = ~(W0 & ~W1 & ~S0 & ~t0);
    int psc = __popcll(cmsk) - 2 * __popcll((xb[jw] ^ cbit) & cmsk);
    psc += __shfl_xor(psc, 1);
    psc += __shfl_xor(psc, 2);
    psc += __shfl_xor(psc, 4);

    int bc = 0, best = __shfl(psc, 0);
    #pragma unroll
    for (int k = 1; k < NCLUST; ++k) {
        int v = __shfl(psc, k * 8);
        if (v > best) { best = v; bc = k; }
    }
    int bt = bc * TPC, bts = __shfl(tscore, bc * TPC);
    #pragma unroll
    for (int k = 1; k < TPC; ++k) {
        int v = __shfl(tscore, bc * TPC + k);
        if (v > bts) { bts = v; bt = bc * TPC + k; }
    }
    if (lane == 0) {
        int slot = atomicAdd(&counts[bt], 1);
        list[(size_t)bt * NTOK + slot] = n;
    }
}

// K3: fused down+spline+up, deep-prefetch variant. 192 blocks x 512 threads.
// launch_bounds(512,1): up to 256 VGPR so the compiler can keep ~32 loads in flight.
__global__ __launch_bounds__(512, 1) void k_ffn(const float* __restrict__ x,
                                                const unsigned short* __restrict__ xn_b,
                                                const unsigned short* __restrict__ wd_b,
                                                const float* __restrict__ sb,
                                                const float* __restrict__ ss,
                                                const unsigned short* __restrict__ wu_b,
                                                const float* __restrict__ scale,
                                                const int* __restrict__ counts,
                                                const int* __restrict__ list,
                                                float* __restrict__ out) {
    int tid = threadIdx.x;
    int lane = tid & 63;
    int wv = tid >> 6;
    int cb = ((int)blockIdx.x & 7) * (NCHUNK_MAX / 8) + ((int)blockIdx.x >> 3);
    int t, base, m;
    if (!route_chunk(counts, lane, cb, t, base, m)) return;   // block-uniform exit

    __shared__ __align__(16) unsigned short hsl[TB * DHID];   // bf16, XOR-swizzled

    int mrow = lane & 15;
    int ko = (lane >> 4) * 8;
    int tokm = list[(size_t)t * NTOK + base + min(mrow, m - 1)];

    // ---- down: load ALL operands first (32 b128 in flight), then MFMA ----
    const unsigned short* xr = xn_b + (size_t)tokm * DIM;
    const unsigned short* wr = wd_b + ((size_t)t * DHID + wv * 16 + mrow) * DIM;
    bf16x8 wreg[16], areg[16];
    #pragma unroll
    for (int kk = 0; kk < 16; ++kk) {
        int d = kk * 32 + ko;
        wreg[kk] = *(const bf16x8*)(wr + d);
        areg[kk] = *(const bf16x8*)(xr + d);
    }
    f32x4 acc0 = {0.f, 0.f, 0.f, 0.f}, acc1 = acc0;
    #pragma unroll
    for (int kk = 0; kk < 8; ++kk) {
        acc0 = __builtin_amdgcn_mfma_f32_16x16x32_bf16(areg[2 * kk], wreg[2 * kk], acc0, 0, 0, 0);
        acc1 = __builtin_amdgcn_mfma_f32_16x16x32_bf16(areg[2 * kk + 1], wreg[2 * kk + 1], acc1, 0, 0, 0);
    }
    f32x4 acc = acc0 + acc1;

    // prefetch ALL up-phase Wu-bf16 rows (16 b128) before spline + barrier
    bf16x8 wupf[16];
    #pragma unroll
    for (int nt = 0; nt < 4; ++nt) {
        const unsigned short* wru = wu_b + ((size_t)t * DIM + wv * 64 + nt * 16 + mrow) * DHID;
        #pragma unroll
        for (int kk = 0; kk < 4; ++kk)
            wupf[nt * 4 + kk] = *(const bf16x8*)(wru + kk * 32 + ko);
    }

    // spline on C fragments -> LDS (rows tr>=m hold duplicated last token: valid bytes)
    int dh = wv * 16 + mrow;
    const float* sbt = sb + ((size_t)t * DHID + dh) * GRID_SZ;
    const float* sst = ss + ((size_t)t * DHID + dh) * GRID_SZ;
    #pragma unroll
    for (int r = 0; r < 4; ++r) {
        int tr = (lane >> 4) * 4 + r;
        float h = acc[r];
        float hn = 1.f / (1.f + expf(-h));
        float g = hn * (float)GRID_SZ;
        int idx = (int)g;
        idx = idx > GRID_SZ - 1 ? GRID_SZ - 1 : idx;
        float lp = g - (float)idx;
        float val = sbt[idx] + sst[idx] * lp;
        hsl[(tr * DHID + dh) ^ ((tr & 7) << 3)] = bf16bits(val);
    }
    __syncthreads();

    // ---- up: d-slice wv (4 independent n-tiles x 4 MFMA, K=128) ----
    float sc_t = scale[t];
    bf16x8 a2[4];
    #pragma unroll
    for (int kk = 0; kk < 4; ++kk)
        a2[kk] = *(const bf16x8*)&hsl[(mrow * DHID + kk * 32 + ko) ^ ((mrow & 7) << 3)];
    #pragma unroll
    for (int nt = 0; nt < 4; ++nt) {
        int d = wv * 64 + nt * 16 + mrow;
        f32x4 au = {0.f, 0.f, 0.f, 0.f};
        #pragma unroll
        for (int kk = 0; kk < 4; ++kk)
            au = __builtin_amdgcn_mfma_f32_16x16x32_bf16(a2[kk], wupf[nt * 4 + kk], au, 0, 0, 0);
        #pragma unroll
        for (int r = 0; r < 4; ++r) {
            int tr = (lane >> 4) * 4 + r;
            int tok_tr = __shfl(tokm, tr);
            if (tr < m) {
                size_t o = (size_t)tok_tr * DIM + d;
                out[o] = x[o] + au[r] * sc_t;
            }
        }
    }
}

extern "C" void kernel_launch(void* const* d_in, const int* in_sizes, int n_in,
                              void* d_out, int out_size, void* d_ws, size_t ws_size,
                              hipStream_t stream) {
    const float* x     = (const float*)d_in[0];
    const float* gamma = (const float*)d_in[1];
    const float* beta  = (const float*)d_in[2];
    const float* Wd    = (const float*)d_in[3];
    const float* sb    = (const float*)d_in[4];
    const float* ss    = (const float*)d_in[5];
    const float* Wu    = (const float*)d_in[6];
    const float* scale = (const float*)d_in[7];
    float* out = (float*)d_out;

    // workspace layout
    u64*   tbits         = (u64*)d_ws;                             // 64*8 u64 = 4 KB
    int*   counts        = (int*)(tbits + NTILES * 8);             // 64 ints
    int*   list          = counts + NTILES;                        // 128K ints
    unsigned short* xn_b = (unsigned short*)(list + (size_t)NTILES * NTOK);  // 1M u16
    unsigned short* wd_b = xn_b + (size_t)NTOK * DIM;              // 4.19M u16
    unsigned short* wu_b = wd_b + (size_t)NTILES * DHID * DIM;     // 4.19M u16

    k_prep<<<576, 512, 0, stream>>>(x, gamma, beta, Wd, Wu, wd_b, wu_b, xn_b, tbits, counts);
    k_route<<<NTOK / 4, 256, 0, stream>>>(xn_b, tbits, counts, list);
    k_ffn<<<NCHUNK_MAX, 512, 0, stream>>>(x, xn_b, wd_b, sb, ss, wu_b, scale, counts, list, out);
}